// Round 11
// baseline (117.715 us; speedup 1.0000x reference)
//
#include <hip/hip_runtime.h>
#include <stdint.h>

// GPTQ 4-bit fused dequant-GEMM, MI355X gfx950.  Round 11 — DIAGNOSTIC + cut.
// M=128, K=4096, N=11008, group=128, g_idx[k]=k>>7 (affine).
//
// R5-R10: six structurally disjoint k_gemm variants (LDS-staged / barrier-free
// / HBM-hoisted / fat-BK / fragment-direct) all land at ~35-50us while every
// mechanistic model says 6-15us -- and k_gemm has been INVISIBLE in the top-5
// since R4 (harness 268MB 0xAA ws-fills @42us occlude it).  R11 makes the
// evidence unavoidable: SPLIT=1 -> 172 blocks x full K (128 steps), ~4x the
// per-dispatch duration -> k_gemm MUST enter the top-5 with full counters.
// Also an unconditional win: k_reduce + 22.5MB partial round-trip deleted;
// out written directly with bias (2 dispatches total).
//  * inner loop = R10 verbatim (fragment-direct A, no LDS, no barriers),
//    but prefetch deepened to 2 steps (A-frags + qweight) since SPLIT=1 runs
//    at ~1 wave/SIMD and latency hiding must come from ILP.
// Counter reads planned: VGPR_Count ~48 + WRITE>>10MB => scratch returned;
// MfmaUtil<5% + WRITE~5.6MB => stall wall; FETCH tells qweight re-read story.

#define M_DIM 128
#define K_DIM 4096
#define N_DIM 11008
#define GS    128
#define STEPS 128                // k32 steps = K/32

typedef _Float16 half8  __attribute__((ext_vector_type(8)));
typedef _Float16 half4t __attribute__((ext_vector_type(4)));
typedef _Float16 half2t __attribute__((ext_vector_type(2)));
typedef float    f32x4  __attribute__((ext_vector_type(4)));

// ---- prep: blocks 0..255 build xf (fragment-major A); 256..1631 build zsc --
// xf slot layout: slot = (m_tile*128 + k_blk)*64 + lane; 8 halfs per slot;
// element j of slot = x[m_tile*16 + (lane&15)][k_blk*32 + (lane>>4)*8 + j].
__global__ void k_prep(const float* __restrict__ x, const int* __restrict__ qzeros,
                       const float* __restrict__ scales,
                       _Float16* __restrict__ xf, half2t* __restrict__ zsc) {
    int b = blockIdx.x, t = threadIdx.x;
    if (b < 256) {                                   // 256*256 = 65536 slots exact
        int slot = b * 256 + t;
        int lane = slot & 63;
        int pair = slot >> 6;                        // m_tile*128 + k_blk
        int mt = pair >> 7, kb = pair & 127;
        int row = mt * 16 + (lane & 15);
        int col = kb * 32 + (lane >> 4) * 8;
        const float* px = x + (size_t)row * K_DIM + col;
        float4 v0 = *(const float4*)px;
        float4 v1 = *(const float4*)(px + 4);
        half8 o;
        o[0] = (_Float16)v0.x; o[1] = (_Float16)v0.y;
        o[2] = (_Float16)v0.z; o[3] = (_Float16)v0.w;
        o[4] = (_Float16)v1.x; o[5] = (_Float16)v1.y;
        o[6] = (_Float16)v1.z; o[7] = (_Float16)v1.w;
        *(half8*)(xf + (size_t)slot * 8) = o;
    } else {                                         // 1376 blocks: 32 g x 43 nb
        b -= 256;
        int g = b / 43;
        int n = (b - g * 43) * 256 + t;              // 43*256 == 11008 exact
        unsigned qz = (unsigned)qzeros[g * (N_DIM / 8) + (n >> 3)];
        float z1 = (float)((qz >> ((n & 7) * 4)) & 15u) + 1.0f;
        float s  = scales[g * N_DIM + n];
        half2t o;
        o[0] = (_Float16)s;
        o[1] = (_Float16)(-z1 * s);
        zsc[g * N_DIM + n] = o;
    }
}

// nibble pair p (nibbles 2p, 2p+1) of q -> two f16 weights:
//  t  = {0x6400|nib_lo, 0x6400|nib_hi<<4} = {1024+q_lo, 1024+16*q_hi}
//  qf = t - 1024                  (EXACT in f16: integers <= 2048)
//  w  = fma(qf, {s, s/16}, {-z1}) where z1 = (z+1)*s
// No pointer casts: pure vector ops, SROA-safe (scratch regression guard).
__device__ __forceinline__ half8 dequant8(unsigned q, half2t S2, half2t Z2) {
    const half2t BIAS = __builtin_bit_cast(half2t, 0x64006400u);
    half2t w[4];
#pragma unroll
    for (int p = 0; p < 4; ++p) {
        unsigned r = __builtin_amdgcn_perm(q, q, 0x00010001u * (unsigned)p); // byte p -> bytes 0,2
        unsigned t = (r & 0x00F0000Fu) | 0x64006400u;                        // v_and_or_b32
        w[p] = __builtin_elementwise_fma(__builtin_bit_cast(half2t, t) - BIAS, S2, Z2);
    }
    half4t w01 = __builtin_shufflevector(w[0], w[1], 0, 1, 2, 3);
    half4t w23 = __builtin_shufflevector(w[2], w[3], 0, 1, 2, 3);
    return __builtin_shufflevector(w01, w23, 0, 1, 2, 3, 4, 5, 6, 7);
}

// ---------------- main fused kernel: no LDS, no barriers, SPLIT=1 ----------
__global__ __launch_bounds__(256, 4)
void k_gemm(const _Float16* __restrict__ xf,     // fragment-major A (1 MB)
            const int*      __restrict__ qweight,// [512][11008] int32
            const half2t*   __restrict__ zsc,    // [32][11008] {s, -(z+1)s}
            const float*    __restrict__ bias,   // [11008]
            float*          __restrict__ out)    // [128][11008]
{
    const int tid  = threadIdx.x;
    const int lane = tid & 63;
    const int w    = tid >> 6;     // 0..3: m_tiles {2w, 2w+1}
    const int q    = lane >> 4;
    const int lr   = lane & 15;

    const int n0 = blockIdx.x * 64;

    int ncol[4];
#pragma unroll
    for (int j = 0; j < 4; ++j) ncol[j] = n0 + j * 16 + lr;

    f32x4 acc[2][4];
#pragma unroll
    for (int f = 0; f < 2; ++f)
#pragma unroll
        for (int j = 0; j < 4; ++j)
            acc[f][j] = (f32x4){0.f, 0.f, 0.f, 0.f};

    // A-frag pointers: frag(mt, k_blk) at xf + (mt*128 + k_blk)*512 + lane*8
    const _Float16* pa0 = xf + (((size_t)(2 * w) * 128) << 9) + lane * 8;
    const _Float16* pa1 = pa0 + ((size_t)128 << 9);
    const int*      pq  = qweight + (size_t)q * N_DIM;   // row(s) = s*4 + q
    const half2t*   pz  = zsc;

    // ---- prologue: 2-deep pipeline (stages s=0,1), z for g=0, bias ----
    half8    A0[2], A1[2];
    unsigned Q[2][4];
    half2t   zc[4];
#pragma unroll
    for (int c = 0; c < 2; ++c) {
        A0[c] = *(const half8*)(pa0 + (size_t)c * 512);
        A1[c] = *(const half8*)(pa1 + (size_t)c * 512);
#pragma unroll
        for (int j = 0; j < 4; ++j)
            Q[c][j] = (unsigned)pq[(size_t)c * 4 * N_DIM + ncol[j]];
    }
#pragma unroll
    for (int j = 0; j < 4; ++j) zc[j] = pz[ncol[j]];
    float bv[4];
#pragma unroll
    for (int j = 0; j < 4; ++j) bv[j] = bias[ncol[j]];

    for (int g = 0; g < 32; ++g) {
        // group constants: S2={s, s/16}, Z2={-z1,-z1}
        const half2t SC = { (_Float16)1.0f, (_Float16)0.0625f };
        half2t S2[4], Z2[4];
#pragma unroll
        for (int j = 0; j < 4; ++j) {
            half2t ss = __builtin_shufflevector(zc[j], zc[j], 0, 0);
            S2[j] = ss * SC;
            Z2[j] = __builtin_shufflevector(zc[j], zc[j], 1, 1);
        }

#pragma unroll
        for (int t = 0; t < 4; ++t) {
            const int s  = g * 4 + t;
            const int c  = s & 1;
            const int sn = (s + 2 < STEPS) ? s + 2 : STEPS - 1;  // uniform clamp

            // ---- issue loads for step s+2 (2-deep, in flight under compute) --
            half8 ta0 = *(const half8*)(pa0 + (size_t)sn * 512);
            half8 ta1 = *(const half8*)(pa1 + (size_t)sn * 512);
            unsigned tq[4];
#pragma unroll
            for (int j = 0; j < 4; ++j)
                tq[j] = (unsigned)pq[(size_t)sn * 4 * N_DIM + ncol[j]];
            half2t nz[4];
            if (t == 3) {
                int gn = (g + 1 < 32) ? g + 1 : g;
#pragma unroll
                for (int j = 0; j < 4; ++j)
                    nz[j] = pz[(size_t)gn * N_DIM + ncol[j]];
            }

            // ---- compute step s ----
#pragma unroll
            for (int j = 0; j < 4; ++j) {
                half8 bf = dequant8(Q[c][j], S2[j], Z2[j]);
                acc[0][j] = __builtin_amdgcn_mfma_f32_16x16x32_f16(A0[c], bf, acc[0][j], 0, 0, 0);
                acc[1][j] = __builtin_amdgcn_mfma_f32_16x16x32_f16(A1[c], bf, acc[1][j], 0, 0, 0);
            }

            // rotate stage c
            A0[c] = ta0; A1[c] = ta1;
#pragma unroll
            for (int j = 0; j < 4; ++j) Q[c][j] = tq[j];
            if (t == 3) {
#pragma unroll
                for (int j = 0; j < 4; ++j) zc[j] = nz[j];
            }
        }
    }

    // ---- epilogue: direct coalesced out + bias (D: row=q*4+r, col=lr) ----
#pragma unroll
    for (int f = 0; f < 2; ++f) {
        int mrow = w * 32 + f * 16 + q * 4;
#pragma unroll
        for (int j = 0; j < 4; ++j)
#pragma unroll
            for (int r = 0; r < 4; ++r)
                out[(size_t)(mrow + r) * N_DIM + ncol[j]] = acc[f][j][r] + bv[j];
    }
}

extern "C" void kernel_launch(void* const* d_in, const int* in_sizes, int n_in,
                              void* d_out, int out_size, void* d_ws, size_t ws_size,
                              hipStream_t stream) {
    const float* x       = (const float*)d_in[0];
    const int*   qweight = (const int*)d_in[1];
    const int*   qzeros  = (const int*)d_in[2];
    const float* scales  = (const float*)d_in[3];
    const float* bias    = (const float*)d_in[4];
    // d_in[5] = g_idx, affine by construction -> unused

    char* ws = (char*)d_ws;
    _Float16* xf  = (_Float16*)ws;             // 1,048,576 B
    half2t*   zsc = (half2t*)(ws + 1048576);   // 1,409,024 B

    k_prep<<<dim3(1632),      dim3(256), 0, stream>>>(x, qzeros, scales, xf, zsc);
    k_gemm<<<dim3(N_DIM/64),  dim3(256), 0, stream>>>(xf, qweight, zsc, bias, (float*)d_out);
}